// Round 7
// baseline (265.610 us; speedup 1.0000x reference)
//
#include <hip/hip_runtime.h>
#include <hip/hip_bf16.h>
#include <stdint.h>

// SimpleAttention: B=4, S=2048, D_IN=D_OUT=1024, fp32 in/out, bf16 MFMA compute.
// out = softmax((x@Wq+bq)(x@Wk+bk)^T / 32) @ (x@Wv+bv)
//
// R17: R16 with the one-line correctness fix. R16's k_scores (256x256)
// dropped the batch offset on the P output pointer -> all 4 batches wrote
// P[0..2047][*] (absmax 8.7e-2). Fixed: Pb = P + b*Ssz*Ssz.
// Perf theory unchanged: 256^2 = 131 FLOP/staged-byte (vs 85 for 128x256),
// grid 256 = 1 block/CU balanced, bn=bid&7 keeps K-strip XCD-L2-resident.
// Same verified 2-barrier BK=32 dbuf template + XOR swizzle.
// Note: __launch_bounds__(512,2) = 2 waves/EU = 8 waves/CU = 1 block/CU.
// Softmax stays fused (R15): P~=exp(s), rowsum partials, pv scales by 1/sum.

#define Bsz 4
#define Ssz 2048
#define Dsz 1024

typedef __attribute__((ext_vector_type(8))) short short8;
typedef __attribute__((ext_vector_type(4))) float floatx4;
typedef const __attribute__((address_space(1))) void* gptr_t;
typedef __attribute__((address_space(3))) void* lptr_t;

__device__ __forceinline__ ushort f32_to_bf16(float f) {
    union { float f; uint32_t u; } c; c.f = f;
    uint32_t u = c.u;
    u += 0x7fffu + ((u >> 16) & 1u);
    return (ushort)(u >> 16);
}

// ---------------------------------------------------------------------------
// Fused QKV (R10, verified ~67 us): C_z = xb(128xK) * Wt_z(128xK)^T, z=0,1,2.
// ---------------------------------------------------------------------------
__global__ __launch_bounds__(256, 2) void k_qkv(
    const ushort* __restrict__ xb, const ushort* __restrict__ Wt,
    const float* __restrict__ bq, const float* __restrict__ bk,
    const float* __restrict__ bv, ushort* __restrict__ QKV,
    ushort* __restrict__ Vt)
{
    __shared__ ushort lsA[2][128 * 32];      // 16 KB
    __shared__ ushort lsB[2][3][128 * 32];   // 48 KB

    const int tid  = threadIdx.x;
    const int bx   = blockIdx.x;             // 0..7  == XCD
    const int by   = blockIdx.y;             // 0..63
    const int row0 = by * 128;
    const int col0 = bx * 128;

    const int lane = tid & 63;
    const int wave = tid >> 6;
    const int wr   = (wave >> 1) * 64;
    const int wc   = (wave & 1) * 64;
    const int m16  = lane & 15;
    const int quad = lane >> 4;

    floatx4 acc[3][4][4];
#pragma unroll
    for (int z = 0; z < 3; z++)
#pragma unroll
        for (int i = 0; i < 4; i++)
#pragma unroll
            for (int j = 0; j < 4; j++) acc[z][i][j] = (floatx4){0.f, 0.f, 0.f, 0.f};

    const int srow = tid >> 2;
    const int skc  = (tid & 3) ^ ((srow >> 1) & 3);
    const ushort* ga = xb + (size_t)(row0 + srow) * Dsz + skc * 8;
    const ushort* gb0 = Wt + (size_t)(col0 + srow) * Dsz + skc * 8;

    const int aoff = (quad ^ ((m16 >> 1) & 3)) * 8;

    __builtin_amdgcn_global_load_lds((gptr_t)(ga),                    (lptr_t)(lsA[0] + tid * 8),        16, 0, 0);
    __builtin_amdgcn_global_load_lds((gptr_t)(ga + (size_t)64 * Dsz), (lptr_t)(lsA[0] + 2048 + tid * 8), 16, 0, 0);
#pragma unroll
    for (int z = 0; z < 3; z++) {
        const ushort* gb = gb0 + (size_t)z * Dsz * Dsz;
        __builtin_amdgcn_global_load_lds((gptr_t)(gb),                    (lptr_t)(lsB[0][z] + tid * 8),        16, 0, 0);
        __builtin_amdgcn_global_load_lds((gptr_t)(gb + (size_t)64 * Dsz), (lptr_t)(lsB[0][z] + 2048 + tid * 8), 16, 0, 0);
    }

    for (int k0 = 0; k0 < Dsz; k0 += 32) {
        const int cur = (k0 >> 5) & 1;
        __syncthreads();
        if (k0 + 32 < Dsz) {
            const int nxt = cur ^ 1;
            const int kn = k0 + 32;
            __builtin_amdgcn_global_load_lds((gptr_t)(ga + kn),                    (lptr_t)(lsA[nxt] + tid * 8),        16, 0, 0);
            __builtin_amdgcn_global_load_lds((gptr_t)(ga + kn + (size_t)64 * Dsz), (lptr_t)(lsA[nxt] + 2048 + tid * 8), 16, 0, 0);
#pragma unroll
            for (int z = 0; z < 3; z++) {
                const ushort* gb = gb0 + (size_t)z * Dsz * Dsz + kn;
                __builtin_amdgcn_global_load_lds((gptr_t)(gb),                    (lptr_t)(lsB[nxt][z] + tid * 8),        16, 0, 0);
                __builtin_amdgcn_global_load_lds((gptr_t)(gb + (size_t)64 * Dsz), (lptr_t)(lsB[nxt][z] + 2048 + tid * 8), 16, 0, 0);
            }
        }

        short8 af[4];
#pragma unroll
        for (int mi = 0; mi < 4; mi++)
            af[mi] = *(const short8*)&lsA[cur][(wr + mi * 16 + m16) * 32 + aoff];
#pragma unroll
        for (int z = 0; z < 3; z++) {
            short8 bfr[4];
#pragma unroll
            for (int ni = 0; ni < 4; ni++)
                bfr[ni] = *(const short8*)&lsB[cur][z][(wc + ni * 16 + m16) * 32 + aoff];
#pragma unroll
            for (int mi = 0; mi < 4; mi++)
#pragma unroll
                for (int ni = 0; ni < 4; ni++)
                    acc[z][mi][ni] = __builtin_amdgcn_mfma_f32_16x16x32_bf16(af[mi], bfr[ni], acc[z][mi][ni], 0, 0, 0);
        }
    }

    // epilogue. C/D: col = m16 (lane), row = quad*4 + reg.
#pragma unroll
    for (int ni = 0; ni < 4; ni++) {
        const int gcol = col0 + wc + ni * 16 + m16;
        const float bqv = bq[gcol], bkv = bk[gcol], bvv = bv[gcol];
#pragma unroll
        for (int mi = 0; mi < 4; mi++) {
            const int grow0 = row0 + wr + mi * 16 + quad * 4;   // global row 0..8191
            ushort4 vpack;
#pragma unroll
            for (int j = 0; j < 4; j++) {
                QKV[(size_t)(grow0 + j) * Dsz + gcol] = f32_to_bf16((acc[0][mi][ni][j] + bqv) * 0.03125f);
                QKV[(size_t)(Bsz * Ssz) * Dsz + (size_t)(grow0 + j) * Dsz + gcol] = f32_to_bf16(acc[1][mi][ni][j] + bkv);
                const ushort vv = f32_to_bf16(acc[2][mi][ni][j] + bvv);
                if (j == 0) vpack.x = vv; else if (j == 1) vpack.y = vv;
                else if (j == 2) vpack.z = vv; else vpack.w = vv;
            }
            const int batch = grow0 >> 11;
            const int s0 = grow0 & (Ssz - 1);
            *(ushort4*)&Vt[(size_t)batch * Dsz * Ssz + (size_t)gcol * Ssz + s0] = vpack;
        }
    }
}

// ---------------------------------------------------------------------------
// k_scores core: 256x256 @ 512 thr (8 waves 2Mx4N, wave 128x64).
// C = exp(Q(256xK) @ K(256xK)^T) bf16 + per-block rowsum partials.
// LDS: A,B dbuf 2x16KB each (64 KB) + red 4 KB. 4 glds/iter (32 KB) feeds
// 256 MFMA -> 131 FLOP/staged-byte.
// ---------------------------------------------------------------------------
__global__ __launch_bounds__(512, 2) void k_scores(
    const ushort* __restrict__ QKV, ushort* __restrict__ P,
    float* __restrict__ partial)
{
    __shared__ ushort lsA[2][256 * 32];   // 32 KB
    __shared__ ushort lsB[2][256 * 32];   // 32 KB
    __shared__ float  red[4][256];        // 4 KB

    const int bid = blockIdx.x;           // 0..255
    const int bn  = bid & 7;              // XCD-local: same-XCD blocks share K-strip
    const int i   = bid >> 3;             // 0..31
    const int bm  = i & 7;
    const int b   = i >> 3;
    const int row0 = bm * 256;
    const int col0 = bn * 256;

    const ushort* A  = QKV + (size_t)b * Ssz * Dsz;          // Q
    const ushort* Bt = QKV + (size_t)(Bsz + b) * Ssz * Dsz;  // K
    ushort* Pb = P + (size_t)b * Ssz * Ssz;                  // R17 FIX: batch offset

    const int tid  = threadIdx.x;
    const int lane = tid & 63;
    const int wave = tid >> 6;
    const int wr   = (wave >> 2) * 128;   // 0,128
    const int wc   = (wave & 3) * 64;     // 0..192
    const int m16  = lane & 15;
    const int quad = lane >> 4;

    floatx4 acc[8][4];
#pragma unroll
    for (int mi = 0; mi < 8; mi++)
#pragma unroll
        for (int ni = 0; ni < 4; ni++) acc[mi][ni] = (floatx4){0.f, 0.f, 0.f, 0.f};

    // staging: 512 thr x 16 B = 8 KB = 128 rows/op; 2 ops per operand tile.
    const int srow = tid >> 2;                        // 0..127
    const int skc  = (tid & 3) ^ ((srow >> 1) & 3);   // XOR swizzle (row+128 preserves it)
    const ushort* ga = A  + (size_t)(row0 + srow) * Dsz + skc * 8;
    const ushort* gb = Bt + (size_t)(col0 + srow) * Dsz + skc * 8;
    const int aoff = (quad ^ ((m16 >> 1) & 3)) * 8;

    __builtin_amdgcn_global_load_lds((gptr_t)(ga),                      (lptr_t)(lsA[0] + tid * 8),        16, 0, 0);
    __builtin_amdgcn_global_load_lds((gptr_t)(ga + (size_t)128 * Dsz),  (lptr_t)(lsA[0] + 4096 + tid * 8), 16, 0, 0);
    __builtin_amdgcn_global_load_lds((gptr_t)(gb),                      (lptr_t)(lsB[0] + tid * 8),        16, 0, 0);
    __builtin_amdgcn_global_load_lds((gptr_t)(gb + (size_t)128 * Dsz),  (lptr_t)(lsB[0] + 4096 + tid * 8), 16, 0, 0);

    for (int k0 = 0; k0 < Dsz; k0 += 32) {
        const int cur = (k0 >> 5) & 1;
        __syncthreads();
        if (k0 + 32 < Dsz) {
            const int nxt = cur ^ 1;
            const int kn = k0 + 32;
            __builtin_amdgcn_global_load_lds((gptr_t)(ga + kn),                      (lptr_t)(lsA[nxt] + tid * 8),        16, 0, 0);
            __builtin_amdgcn_global_load_lds((gptr_t)(ga + kn + (size_t)128 * Dsz),  (lptr_t)(lsA[nxt] + 4096 + tid * 8), 16, 0, 0);
            __builtin_amdgcn_global_load_lds((gptr_t)(gb + kn),                      (lptr_t)(lsB[nxt] + tid * 8),        16, 0, 0);
            __builtin_amdgcn_global_load_lds((gptr_t)(gb + kn + (size_t)128 * Dsz),  (lptr_t)(lsB[nxt] + 4096 + tid * 8), 16, 0, 0);
        }

        short8 af[8], bfr[4];
#pragma unroll
        for (int mi = 0; mi < 8; mi++)
            af[mi] = *(const short8*)&lsA[cur][(wr + mi * 16 + m16) * 32 + aoff];
#pragma unroll
        for (int ni = 0; ni < 4; ni++)
            bfr[ni] = *(const short8*)&lsB[cur][(wc + ni * 16 + m16) * 32 + aoff];
#pragma unroll
        for (int mi = 0; mi < 8; mi++)
#pragma unroll
            for (int ni = 0; ni < 4; ni++)
                acc[mi][ni] = __builtin_amdgcn_mfma_f32_16x16x32_bf16(af[mi], bfr[ni], acc[mi][ni], 0, 0, 0);
    }

    // epilogue: P~ = exp(acc) bf16 + deterministic rowsum partials
    float rs[8][4];
#pragma unroll
    for (int mi = 0; mi < 8; mi++)
#pragma unroll
        for (int j = 0; j < 4; j++) rs[mi][j] = 0.f;
#pragma unroll
    for (int ni = 0; ni < 4; ni++) {
        const int gcol = col0 + wc + ni * 16 + m16;
#pragma unroll
        for (int mi = 0; mi < 8; mi++) {
            const int grow0 = row0 + wr + mi * 16 + quad * 4;
#pragma unroll
            for (int j = 0; j < 4; j++) {
                const float e = __expf(acc[mi][ni][j]);
                Pb[(size_t)(grow0 + j) * Ssz + gcol] = f32_to_bf16(e);
                rs[mi][j] += e;
            }
        }
    }
    // butterfly over the 16-lane col group; lane m16==0 holds the 64-col sum
#pragma unroll
    for (int mi = 0; mi < 8; mi++)
#pragma unroll
        for (int j = 0; j < 4; j++) {
            float v = rs[mi][j];
            v += __shfl_xor(v, 1, 64);
            v += __shfl_xor(v, 2, 64);
            v += __shfl_xor(v, 4, 64);
            v += __shfl_xor(v, 8, 64);
            if (m16 == 0) red[wave & 3][wr + mi * 16 + quad * 4 + j] = v;
        }
    __syncthreads();
    if (tid < 256) {
        const float s = red[0][tid] + red[1][tid] + red[2][tid] + red[3][tid];
        partial[(((size_t)b * 8 + bm) * 8 + bn) * 256 + tid] = s;
    }
}

// ---------------------------------------------------------------------------
// k_pv core (R14/R15 verified): 128x256 @ 512 thr, out scaled by 1/rowsum.
// ---------------------------------------------------------------------------
__global__ __launch_bounds__(512, 1) void k_pv(
    const ushort* __restrict__ P, const ushort* __restrict__ Vt,
    const float* __restrict__ partial, float* __restrict__ out)
{
    __shared__ ushort lsA[2][128 * 32];   // 16 KB
    __shared__ ushort lsB[2][256 * 32];   // 32 KB
    __shared__ float  invs[128];

    const int bid = blockIdx.x;
    const int c   = bid & 7;
    const int i   = bid >> 3;           // 0..31
    const int bx  = i & 3;
    const int sid = c * 8 + (i >> 2);   // 0..63
    const int by  = sid & 15;
    const int b   = sid >> 4;
    const int row0 = by * 128;
    const int col0 = bx * 256;

    const ushort* A  = P  + (size_t)b * Ssz * Ssz;
    const ushort* Bt = Vt + (size_t)b * Dsz * Ssz;
    float* Cout = out + (size_t)b * Ssz * Dsz;
    const float* pin = partial + (size_t)b * 8 * 8 * 256;

    const int tid  = threadIdx.x;
    const int lane = tid & 63;
    const int wave = tid >> 6;
    const int wr   = (wave >> 2) * 64;
    const int wc   = (wave & 3) * 64;
    const int m16  = lane & 15;
    const int quad = lane >> 4;

    floatx4 acc[4][4];
#pragma unroll
    for (int i2 = 0; i2 < 4; i2++)
#pragma unroll
        for (int j = 0; j < 4; j++) acc[i2][j] = (floatx4){0.f, 0.f, 0.f, 0.f};

    if (tid < 128) {
        const int r = row0 + tid;
        const float* pb = pin + ((size_t)(r >> 8) * 8) * 256 + (r & 255);
        float s = 0.f;
#pragma unroll
        for (int bn = 0; bn < 8; bn++) s += pb[bn * 256];
        invs[tid] = 1.0f / s;
    }

    const int srow = tid >> 2;
    const int skc  = (tid & 3) ^ ((srow >> 1) & 3);
    const ushort* ga = A  + (size_t)(row0 + srow) * Ssz + skc * 8;
    const ushort* gb = Bt + (size_t)(col0 + srow) * Ssz + skc * 8;
    const int aoff = (quad ^ ((m16 >> 1) & 3)) * 8;

    __builtin_amdgcn_global_load_lds((gptr_t)(ga),                      (lptr_t)(lsA[0] + tid * 8),        16, 0, 0);
    __builtin_amdgcn_global_load_lds((gptr_t)(gb),                      (lptr_t)(lsB[0] + tid * 8),        16, 0, 0);
    __builtin_amdgcn_global_load_lds((gptr_t)(gb + (size_t)128 * Ssz),  (lptr_t)(lsB[0] + 4096 + tid * 8), 16, 0, 0);

    for (int k0 = 0; k0 < Ssz; k0 += 32) {
        const int cur = (k0 >> 5) & 1;
        __syncthreads();
        if (k0 + 32 < Ssz) {
            const int nxt = cur ^ 1;
            const int kn = k0 + 32;
            __builtin_amdgcn_global_load_lds((gptr_t)(ga + kn),                      (lptr_t)(lsA[nxt] + tid * 8),        16, 0, 0);
            __builtin_amdgcn_global_load_lds((gptr_t)(gb + kn),                      (lptr_t)(lsB[nxt] + tid * 8),        16, 0, 0);
            __builtin_amdgcn_global_load_lds((gptr_t)(gb + kn + (size_t)128 * Ssz),  (lptr_t)(lsB[nxt] + 4096 + tid * 8), 16, 0, 0);
        }

        short8 af[4], bfr[4];
#pragma unroll
        for (int mi = 0; mi < 4; mi++)
            af[mi] = *(const short8*)&lsA[cur][(wr + mi * 16 + m16) * 32 + aoff];
#pragma unroll
        for (int ni = 0; ni < 4; ni++)
            bfr[ni] = *(const short8*)&lsB[cur][(wc + ni * 16 + m16) * 32 + aoff];
#pragma unroll
        for (int mi = 0; mi < 4; mi++)
#pragma unroll
            for (int ni = 0; ni < 4; ni++)
                acc[mi][ni] = __builtin_amdgcn_mfma_f32_16x16x32_bf16(af[mi], bfr[ni], acc[mi][ni], 0, 0, 0);
    }

#pragma unroll
    for (int ni = 0; ni < 4; ni++) {
        const int gcol = col0 + wc + ni * 16 + m16;
#pragma unroll
        for (int mi = 0; mi < 4; mi++) {
            const int grow0 = row0 + wr + mi * 16 + quad * 4;
            const int rl0   = wr + mi * 16 + quad * 4;
#pragma unroll
            for (int j = 0; j < 4; j++)
                Cout[(size_t)(grow0 + j) * Dsz + gcol] = acc[mi][ni][j] * invs[rl0 + j];
        }
    }
}

// ---------------------------------------------------------------------------
// prep: (bid < 8192)  x fp32 -> bf16
//       (bid >= 8192) W [K][N] fp32 -> Wt [N][K] bf16 for Wq/Wk/Wv
__global__ __launch_bounds__(256) void k_prep(
    const float* __restrict__ x, ushort* __restrict__ xb,
    const float* __restrict__ Wq, const float* __restrict__ Wk,
    const float* __restrict__ Wv, ushort* __restrict__ Wt)
{
    __shared__ float tile[32][33];
    const int bid = blockIdx.x;
    const int tid = threadIdx.x;
    if (bid < 8192) {
        int i = (bid * 256 + tid) * 4;
        float4 v = *(const float4*)(x + i);
        ushort4 o;
        o.x = f32_to_bf16(v.x); o.y = f32_to_bf16(v.y);
        o.z = f32_to_bf16(v.z); o.w = f32_to_bf16(v.w);
        *(ushort4*)(xb + i) = o;
    } else {
        const int wb = bid - 8192;
        const int z  = wb >> 10;
        const int r  = wb & 1023;
        const int nb = (r & 31) * 32;
        const int kb = (r >> 5) * 32;
        const float* W = (z == 0) ? Wq : ((z == 1) ? Wk : Wv);
        ushort* out = Wt + (size_t)z * Dsz * Dsz;
        const int tx = tid & 31, ty = tid >> 5;
#pragma unroll
        for (int j = 0; j < 32; j += 8)
            tile[ty + j][tx] = W[(size_t)(kb + ty + j) * Dsz + nb + tx];
        __syncthreads();
#pragma unroll
        for (int j = 0; j < 32; j += 8)
            out[(size_t)(nb + ty + j) * Dsz + kb + tx] = f32_to_bf16(tile[tx][ty + j]);
    }
}

// ---------------------------------------------------------------------------
extern "C" void kernel_launch(void* const* d_in, const int* in_sizes, int n_in,
                              void* d_out, int out_size, void* d_ws, size_t ws_size,
                              hipStream_t stream) {
    const float* x  = (const float*)d_in[0];
    const float* Wq = (const float*)d_in[1];
    const float* bq = (const float*)d_in[2];
    const float* Wk = (const float*)d_in[3];
    const float* bk = (const float*)d_in[4];
    const float* Wv = (const float*)d_in[5];
    const float* bv = (const float*)d_in[6];
    float* out = (float*)d_out;

    // workspace layout (bytes)
    char* ws = (char*)d_ws;
    ushort* xb      = (ushort*)(ws);                        // 16,777,216
    ushort* Wt      = (ushort*)(ws + 16777216);             //  6,291,456
    ushort* QKV     = (ushort*)(ws + 23068672);             // 33,554,432 (Q+K)
    ushort* Vt      = (ushort*)(ws + 73400320);             // 16,777,216
    ushort* P       = (ushort*)(ws + 90177536);             // 33,554,432 (bf16 P~)
    float*  partial = (float*) (ws + 123731968);            //    262,144

    k_prep<<<dim3(8192 + 3072), dim3(256), 0, stream>>>(x, xb, Wq, Wk, Wv, Wt);
    k_qkv<<<dim3(Dsz / 128, Bsz * Ssz / 128), dim3(256), 0, stream>>>(xb, Wt, bq, bk, bv, QKV, Vt);
    k_scores<<<dim3(256), dim3(512), 0, stream>>>(QKV, P, partial);
    k_pv<<<dim3(256), dim3(512), 0, stream>>>(P, Vt, partial, out);
}